// Round 1
// baseline (571.133 us; speedup 1.0000x reference)
//
#include <hip/hip_runtime.h>

// Problem constants (from reference): D=128, B=2048, C=512.
// Output: [B, 2C] fp32 where out[b,0:C] = (size==D ? buffer[head,b,:] : 0),
//         out[b,C:2C] = x[b,:].
constexpr int D = 128;
constexpr int B = 2048;
constexpr int C = 512;
constexpr int C4 = C / 4;        // 128 float4 per half-row
constexpr int W4 = 2 * C4;       // 256 float4 per output row
constexpr int TOTAL4 = B * W4;   // 524288 float4 total

__global__ __launch_bounds__(256)
void causal_queue_concat(const float4* __restrict__ x,
                         const float4* __restrict__ buf,
                         const int* __restrict__ size_p,
                         const int* __restrict__ head_p,
                         float4* __restrict__ out) {
    const int i = blockIdx.x * blockDim.x + threadIdx.x;   // [0, TOTAL4)
    const int b  = i >> 8;        // / W4 (=256)
    const int c4 = i & (W4 - 1);  // % 256

    float4 v;
    if (c4 < C4) {
        // x_past half: buffer[head, b, :] when full, else zeros.
        // Wave-uniform branch: 64 consecutive i share the same half.
        const bool full = (size_p[0] == D);
        if (full) {
            const int head = head_p[0];
            v = buf[(size_t)head * (B * C4) + (size_t)b * C4 + c4];
        } else {
            v = make_float4(0.f, 0.f, 0.f, 0.f);
        }
    } else {
        // x half
        v = x[(size_t)b * C4 + (c4 - C4)];
    }
    out[i] = v;
}

extern "C" void kernel_launch(void* const* d_in, const int* in_sizes, int n_in,
                              void* d_out, int out_size, void* d_ws, size_t ws_size,
                              hipStream_t stream) {
    const float4* x     = (const float4*)d_in[0];   // [B, C] fp32
    const float4* buf   = (const float4*)d_in[1];   // [D, B, C] fp32
    const int*    sizep = (const int*)d_in[2];      // scalar
    const int*    headp = (const int*)d_in[3];      // scalar
    float4*       out   = (float4*)d_out;           // [B, 2C] fp32

    constexpr int BLOCK = 256;
    constexpr int GRID  = TOTAL4 / BLOCK;           // 2048 blocks
    causal_queue_concat<<<GRID, BLOCK, 0, stream>>>(x, buf, sizep, headp, out);
}